// Round 3
// baseline (342.055 us; speedup 1.0000x reference)
//
#include <hip/hip_runtime.h>

// Mamba-2 SSD chunked scan. b=4, s=8192, h=32, p=64, n=16, l=64, c=128.
// Segment decomposition: 2048 segments of SEG=8 chunks.
#define BB 4
#define SS 8192
#define HH 32
#define PP 64
#define NN 16
#define LL 64
#define CC 128
#define SEG 8
#define NSEG (CC / SEG)          // 16 segments per chain
#define NCHAIN (BB * HH)         // 128 chains
#define NSEGT (NCHAIN * NSEG)    // 2048 segments total

typedef __attribute__((ext_vector_type(8))) short bf16x8;
typedef __attribute__((ext_vector_type(4))) float f32x4;

__device__ inline short f2bf(float f) {
    unsigned u = __builtin_bit_cast(unsigned, f);
    u = (u + 0x7FFFu + ((u >> 16) & 1u)) >> 16;
    return (short)u;
}

// ---------------------------------------------------------------------------
// K1: per segment -> carry S_seg[p][n] (f32) and sum of alast over segment.
// P = 0; per chunk: P = exp(alast)*P + sum_l X[l][p]*exp(alast-cs_l)*B[l][n]
// ---------------------------------------------------------------------------
__global__ __launch_bounds__(256) void k1_carries(
    const float* __restrict__ X, const float* __restrict__ A,
    const float* __restrict__ B, float* __restrict__ carry,
    float* __restrict__ segd)
{
    int seg = blockIdx.x;
    int chain = seg >> 4;            // / NSEG
    int kseg = seg & (NSEG - 1);
    int h = chain & (HH - 1);
    int b = chain >> 5;
    int tid = threadIdx.x;

    __shared__ float Xs[LL][PP];
    __shared__ float Bs[LL][NN];
    __shared__ float csL[LL];
    __shared__ float wl[LL];

    int p = tid >> 2, nb = (tid & 3) << 2;
    float P0 = 0.f, P1 = 0.f, P2 = 0.f, P3 = 0.f;
    float asum = 0.f;

    for (int cc = 0; cc < SEG; ++cc) {
        int c = kseg * SEG + cc;
        size_t row0 = (size_t)b * SS + (size_t)c * LL;
        const float* Xp = X + (row0 * HH + h) * PP;
        const float* Bp = B + (row0 * HH + h) * NN;
        const float* Ap = A + row0 * HH + h;

#pragma unroll
        for (int kk = 0; kk < 16; ++kk) {
            int e = tid + kk * 256;
            Xs[e >> 6][e & 63] = Xp[(size_t)(e >> 6) * (HH * PP) + (e & 63)];
        }
#pragma unroll
        for (int kk = 0; kk < 4; ++kk) {
            int e = tid + kk * 256;
            Bs[e >> 4][e & 15] = Bp[(size_t)(e >> 4) * (HH * NN) + (e & 15)];
        }
        if (tid < 64) {
            float x = Ap[(size_t)tid * HH];
#pragma unroll
            for (int d = 1; d < 64; d <<= 1) {
                float t = __shfl_up(x, d, 64);
                if (tid >= d) x += t;
            }
            csL[tid] = x;
            float alast = __shfl(x, 63, 64);
            wl[tid] = __expf(alast - x);
        }
        __syncthreads();

        float alast = csL[LL - 1];
        float s0 = 0.f, s1 = 0.f, s2 = 0.f, s3 = 0.f;
        for (int l = 0; l < LL; ++l) {
            float xw = Xs[l][p] * wl[l];
            const float4 bv = *(const float4*)&Bs[l][nb];
            s0 += xw * bv.x; s1 += xw * bv.y;
            s2 += xw * bv.z; s3 += xw * bv.w;
        }
        float ea = __expf(alast);
        P0 = ea * P0 + s0; P1 = ea * P1 + s1;
        P2 = ea * P2 + s2; P3 = ea * P3 + s3;
        asum += alast;
        __syncthreads();   // before next chunk's staging overwrites LDS
    }
    float4 pv = {P0, P1, P2, P3};
    *(float4*)(carry + (size_t)seg * (PP * NN) + tid * 4) = pv;
    if (tid == 0) segd[seg] = asum;
}

// ---------------------------------------------------------------------------
// K2: per chain, scan NSEG=16 segment carries -> incoming prefix per segment.
// 512 blocks: (chain, quarter of the 1024 pn elements).
// ---------------------------------------------------------------------------
__global__ __launch_bounds__(256) void k2_scan(
    const float* __restrict__ carry, const float* __restrict__ segd,
    float* __restrict__ pin)
{
    int chain = blockIdx.x >> 2;
    int t = ((blockIdx.x & 3) << 8) + threadIdx.x;    // 0..1023
    const float* cb = carry + (size_t)chain * NSEG * (PP * NN) + t;
    float* pb = pin + (size_t)chain * NSEG * (PP * NN) + t;
    const float* as = segd + chain * NSEG;
    float P = 0.f;
    for (int kk = 0; kk < NSEG; ++kk) {
        float s = cb[(size_t)kk * (PP * NN)];
        pb[(size_t)kk * (PP * NN)] = P;
        P = __expf(as[kk]) * P + s;
    }
}

// ---------------------------------------------------------------------------
// K3: per segment, walk 8 chunks sequentially with register-resident P.
// Per chunk: scores MFMA -> ScF; Yoff = C*P^T (P via bf16 LDS publish);
// Ydiag = Sc*X; S^T = (decayed B^T)*X^T MFMA -> P update; store Y.
// ---------------------------------------------------------------------------
__global__ __launch_bounds__(256) void k3_y(
    const float* __restrict__ X, const float* __restrict__ A,
    const float* __restrict__ Bm, const float* __restrict__ Cm,
    const float* __restrict__ pin, float* __restrict__ Y)
{
    int seg = blockIdx.x;
    int chain = seg >> 4;
    int kseg = seg & (NSEG - 1);
    int h = chain & (HH - 1);
    int b = chain >> 5;
    int tid = threadIdx.x;
    int w = tid >> 6, l = tid & 63, g = l >> 4, lr = l & 15;

    __shared__ short XTF[8 * 64 * 8];   // X^T B-frags: slot (kt*4+pt)*64+lane
    __shared__ short ScF[8 * 64 * 8];   // score A-frags: slot (w*2+kt)*64+lane
    __shared__ float Bp32[LL][17];      // plain B chunk, +1 pad
    __shared__ short PT16[NN * 68];     // P^T bf16 [n][p], row pad 68
    __shared__ float csL[LL];
    __shared__ float wl[LL];

    // zero ScF once (upper-triangular tiles never written stay zero)
    ((bf16x8*)ScF)[tid] = (bf16x8)0;
    ((bf16x8*)ScF)[tid + 256] = (bf16x8)0;

    // P regs from pin: P[r] = pin[seg][p=16w+lr][n=4g+r]
    float4 pv = *(const float4*)(pin + (size_t)seg * (PP * NN) + (16 * w + lr) * NN + 4 * g);
    float P[4] = {pv.x, pv.y, pv.z, pv.w};

    for (int cc = 0; cc < SEG; ++cc) {
        int c = kseg * SEG + cc;
        size_t row0 = (size_t)b * SS + (size_t)c * LL;
        const float* Xp = X + (row0 * HH + h) * PP;
        const float* Bp = Bm + (row0 * HH + h) * NN;
        const float* Cp = Cm + (row0 * HH + h) * NN;
        const float* Ap = A + row0 * HH + h;
        float* Yp = Y + (row0 * HH + h) * PP;

        // ---- E0: publish current P to PT16; stage chunk operands ----
#pragma unroll
        for (int r = 0; r < 4; ++r)
            PT16[(4 * g + r) * 68 + 16 * w + lr] = f2bf(P[r]);

        if (tid < 64) {
            float x = Ap[(size_t)tid * HH];
#pragma unroll
            for (int d = 1; d < 64; d <<= 1) {
                float t = __shfl_up(x, d, 64);
                if (tid >= d) x += t;
            }
            csL[tid] = x;
            float alast = __shfl(x, 63, 64);
            wl[tid] = __expf(alast - x);
        }
#pragma unroll
        for (int kk = 0; kk < 4; ++kk) {
            int e = tid + kk * 256;
            Bp32[e >> 4][e & 15] = Bp[(size_t)(e >> 4) * (HH * NN) + (e & 15)];
        }
#pragma unroll
        for (int si = 0; si < 2; ++si) {
            int s = tid + si * 256;
            int sl = s & 63, pt = (s >> 6) & 3, kt = s >> 8;
            int pp = pt * 16 + (sl & 15);
            int k0 = kt * 32 + (sl >> 4) * 8;
            bf16x8 xb;
#pragma unroll
            for (int e = 0; e < 8; ++e)
                xb[e] = f2bf(Xp[(size_t)(k0 + e) * (HH * PP) + pp]);
            ((bf16x8*)XTF)[s] = xb;
        }
        bf16x8 caw = (bf16x8)0;
        if (g < 2) {
            const float* cr = Cp + (size_t)(16 * w + lr) * (HH * NN) + g * 8;
            float4 a0 = *(const float4*)cr;
            float4 a1 = *(const float4*)(cr + 4);
            caw[0] = f2bf(a0.x); caw[1] = f2bf(a0.y);
            caw[2] = f2bf(a0.z); caw[3] = f2bf(a0.w);
            caw[4] = f2bf(a1.x); caw[5] = f2bf(a1.y);
            caw[6] = f2bf(a1.z); caw[7] = f2bf(a1.w);
        }
        __syncthreads();

        // ---- E1: compute ----
        float alast = csL[LL - 1];
        float cs_i[4], ei[4];
        int ib = 16 * w + 4 * g;
#pragma unroll
        for (int r = 0; r < 4; ++r) { cs_i[r] = csL[ib + r]; ei[r] = __expf(cs_i[r]); }

        // P B-frags from PT16 (zeros for k>=16)
        bf16x8 pf[4];
#pragma unroll
        for (int pt = 0; pt < 4; ++pt) {
            bf16x8 t = (bf16x8)0;
            if (g < 2) {
#pragma unroll
                for (int e = 0; e < 8; ++e)
                    t[e] = PT16[(g * 8 + e) * 68 + pt * 16 + lr];
            }
            pf[pt] = t;
        }
        // decayed B^T A-frags (in registers, per wave)
        bf16x8 bt[2];
#pragma unroll
        for (int kt = 0; kt < 2; ++kt) {
            bf16x8 t;
#pragma unroll
            for (int e = 0; e < 8; ++e) {
                int ll = kt * 32 + g * 8 + e;
                t[e] = f2bf(Bp32[ll][lr] * wl[ll]);
            }
            bt[kt] = t;
        }

        // scores: Sc[i][j] = (C[i]·B[j]) * exp(cs_i - cs_j), j<=i
        for (int jt = 0; jt <= w; ++jt) {
            bf16x8 bw = (bf16x8)0;
            if (g < 2) {
#pragma unroll
                for (int e = 0; e < 8; ++e)
                    bw[e] = f2bf(Bp32[jt * 16 + lr][g * 8 + e]);
            }
            f32x4 sr = __builtin_amdgcn_mfma_f32_16x16x32_bf16(caw, bw, (f32x4)0.f, 0, 0, 0);
            int j = jt * 16 + lr;
            float csj = csL[j];
            int kt2 = j >> 5;
            int flb = 16 * ((j >> 3) & 3);
#pragma unroll
            for (int r = 0; r < 4; ++r) {
                int i15 = g * 4 + r;
                int i = 16 * w + i15;
                float v = (j <= i) ? sr[r] * __expf(cs_i[r] - csj) : 0.f;
                ScF[((w * 2 + kt2) * 64 + i15 + flb) * 8 + (j & 7)] = f2bf(v);
            }
        }

        // Yoff: acc = C·P^T, scaled by exp(cs_i)
        f32x4 acc[4];
#pragma unroll
        for (int pt = 0; pt < 4; ++pt)
            acc[pt] = __builtin_amdgcn_mfma_f32_16x16x32_bf16(caw, pf[pt], (f32x4)0.f, 0, 0, 0);
#pragma unroll
        for (int pt = 0; pt < 4; ++pt)
#pragma unroll
            for (int r = 0; r < 4; ++r) acc[pt][r] *= ei[r];

        // Ydiag: acc += Sc·X
        int kts = (w >= 2) ? 2 : 1;
        for (int kt = 0; kt < kts; ++kt) {
            bf16x8 af = ((bf16x8*)ScF)[(w * 2 + kt) * 64 + l];
#pragma unroll
            for (int pt = 0; pt < 4; ++pt) {
                bf16x8 xf = ((bf16x8*)XTF)[(kt * 4 + pt) * 64 + l];
                acc[pt] = __builtin_amdgcn_mfma_f32_16x16x32_bf16(af, xf, acc[pt], 0, 0, 0);
            }
        }

        // S^T = (decayed B^T)·X^T -> P update (wave w owns p-strip 16w..16w+15)
        f32x4 st = (f32x4)0.f;
#pragma unroll
        for (int kt = 0; kt < 2; ++kt) {
            bf16x8 xf = ((bf16x8*)XTF)[(kt * 4 + w) * 64 + l];
            st = __builtin_amdgcn_mfma_f32_16x16x32_bf16(bt[kt], xf, st, 0, 0, 0);
        }
        float ea = __expf(alast);
#pragma unroll
        for (int r = 0; r < 4; ++r) P[r] = ea * P[r] + st[r];

        // store Y: i = 16w + 4g + r, p = 16pt + lr
#pragma unroll
        for (int pt = 0; pt < 4; ++pt)
#pragma unroll
            for (int r = 0; r < 4; ++r)
                Yp[(size_t)(16 * w + 4 * g + r) * (HH * PP) + pt * 16 + lr] = acc[pt][r];

        __syncthreads();   // protect LDS (XTF/Bp32/csL/wl/PT16) before restage
    }
}

// ---------------------------------------------------------------------------
extern "C" void kernel_launch(void* const* d_in, const int* in_sizes, int n_in,
                              void* d_out, int out_size, void* d_ws, size_t ws_size,
                              hipStream_t stream)
{
    const float* X = (const float*)d_in[0];
    const float* A = (const float*)d_in[1];
    const float* B = (const float*)d_in[2];
    const float* C = (const float*)d_in[3];
    float* Y = (float*)d_out;

    float* carry = (float*)d_ws;                              // 8 MiB
    float* pin   = carry + (size_t)NSEGT * (PP * NN);         // 8 MiB
    float* segd  = pin   + (size_t)NSEGT * (PP * NN);         // 8 KiB

    dim3 blk(256);
    k1_carries<<<dim3(NSEGT), blk, 0, stream>>>(X, A, B, carry, segd);
    k2_scan<<<dim3(NCHAIN * 4), blk, 0, stream>>>(carry, segd, pin);
    k3_y<<<dim3(NSEGT), blk, 0, stream>>>(X, A, B, C, pin, Y);
}

// Round 4
// 286.430 us; speedup vs baseline: 1.1942x; 1.1942x over previous
//
#include <hip/hip_runtime.h>

// Mamba-2 SSD chunked scan. b=4, s=8192, h=32, p=64, n=16, l=64, c=128.
// Segment decomposition: 4096 segments of SEG=4 chunks, software-pipelined.
#define BB 4
#define SS 8192
#define HH 32
#define PP 64
#define NN 16
#define LL 64
#define CC 128
#define SEG 4
#define NSEG (CC / SEG)          // 32 segments per chain
#define NCHAIN (BB * HH)         // 128 chains
#define NSEGT (NCHAIN * NSEG)    // 4096 segments total

typedef __attribute__((ext_vector_type(8))) short bf16x8;
typedef __attribute__((ext_vector_type(4))) float f32x4;

__device__ inline short f2bf(float f) {
    unsigned u = __builtin_bit_cast(unsigned, f);
    u = (u + 0x7FFFu + ((u >> 16) & 1u)) >> 16;
    return (short)u;
}

// ---------------------------------------------------------------------------
// K1: per segment -> carry S_seg[p][n] and sum of alast. MFMA S^T, pipelined.
// Each wave loads only its own p-strip of X straight to registers.
// ---------------------------------------------------------------------------
__global__ __launch_bounds__(256) void k1_carries(
    const float* __restrict__ X, const float* __restrict__ A,
    const float* __restrict__ B, float* __restrict__ carry,
    float* __restrict__ segd)
{
    int seg = blockIdx.x;
    int chain = seg >> 5;            // / NSEG
    int kseg = seg & (NSEG - 1);
    int h = chain & (HH - 1);
    int b = chain >> 5;
    int tid = threadIdx.x;
    int w = tid >> 6, l = tid & 63, g = l >> 4, lr = l & 15;

    __shared__ float Bs[2][LL][17];
    __shared__ float csL[2][LL];
    __shared__ float wls[2][LL];

    float P[4] = {0.f, 0.f, 0.f, 0.f};
    float asum = 0.f;
    float xr[16]; float4 br; float ar = 0.f;

    int c0 = kseg * SEG;

    auto LOADS = [&](int c) {
        size_t row0 = (size_t)b * SS + (size_t)c * LL;
        const float* Xp = X + (row0 * HH + h) * PP;
        const float* Bp = B + (row0 * HH + h) * NN;
        const float* Ap = A + row0 * HH + h;
#pragma unroll
        for (int kt = 0; kt < 2; ++kt)
#pragma unroll
            for (int e = 0; e < 8; ++e)
                xr[kt * 8 + e] = Xp[(size_t)(kt * 32 + g * 8 + e) * (HH * PP) + 16 * w + lr];
        br = *(const float4*)(Bp + (size_t)(tid >> 2) * (HH * NN) + (tid & 3) * 4);
        if (tid < 64) ar = Ap[(size_t)tid * HH];
    };

    auto WRITE = [&](int q1) {
        if (tid < 64) {
            float x = ar;
#pragma unroll
            for (int d = 1; d < 64; d <<= 1) {
                float t = __shfl_up(x, d, 64);
                if (tid >= d) x += t;
            }
            csL[q1][tid] = x;
            float al2 = __shfl(x, 63, 64);
            wls[q1][tid] = __expf(al2 - x);
        }
        int r = tid >> 2, qq = tid & 3;
        Bs[q1][r][qq * 4 + 0] = br.x;
        Bs[q1][r][qq * 4 + 1] = br.y;
        Bs[q1][r][qq * 4 + 2] = br.z;
        Bs[q1][r][qq * 4 + 3] = br.w;
    };

    LOADS(c0);
    WRITE(0);
    __syncthreads();

    for (int cc = 0; cc < SEG; ++cc) {
        int q = cc & 1;
        // convert own X strip first (frees xr for the next prefetch)
        bf16x8 xf0, xf1;
#pragma unroll
        for (int e = 0; e < 8; ++e) { xf0[e] = f2bf(xr[e]); xf1[e] = f2bf(xr[8 + e]); }
        if (cc + 1 < SEG) LOADS(c0 + cc + 1);

        bf16x8 bt[2];
#pragma unroll
        for (int kt = 0; kt < 2; ++kt) {
            bf16x8 t;
#pragma unroll
            for (int e = 0; e < 8; ++e) {
                int ll2 = kt * 32 + g * 8 + e;
                t[e] = f2bf(Bs[q][ll2][lr] * wls[q][ll2]);
            }
            bt[kt] = t;
        }
        f32x4 st = __builtin_amdgcn_mfma_f32_16x16x32_bf16(bt[0], xf0, (f32x4)0.f, 0, 0, 0);
        st = __builtin_amdgcn_mfma_f32_16x16x32_bf16(bt[1], xf1, st, 0, 0, 0);

        float alast = csL[q][LL - 1];
        float ea = __expf(alast);
#pragma unroll
        for (int r = 0; r < 4; ++r) P[r] = ea * P[r] + st[r];
        asum += alast;

        if (cc + 1 < SEG) WRITE(q ^ 1);
        __syncthreads();
    }

    float4 pv = {P[0], P[1], P[2], P[3]};
    *(float4*)(carry + (size_t)seg * (PP * NN) + (16 * w + lr) * NN + 4 * g) = pv;
    if (tid == 0) segd[seg] = asum;
}

// ---------------------------------------------------------------------------
// K2: per chain, scan NSEG=32 segment carries -> incoming prefix per segment.
// ---------------------------------------------------------------------------
__global__ __launch_bounds__(256) void k2_scan(
    const float* __restrict__ carry, const float* __restrict__ segd,
    float* __restrict__ pin)
{
    int chain = blockIdx.x >> 2;
    int t = ((blockIdx.x & 3) << 8) + threadIdx.x;    // 0..1023
    const float* cb = carry + (size_t)chain * NSEG * (PP * NN) + t;
    float* pb = pin + (size_t)chain * NSEG * (PP * NN) + t;
    const float* as = segd + chain * NSEG;
    float P = 0.f;
    for (int k0 = 0; k0 < NSEG; k0 += 8) {
        float s[8], av[8], o[8];
#pragma unroll
        for (int u = 0; u < 8; ++u) s[u] = cb[(size_t)(k0 + u) * (PP * NN)];
#pragma unroll
        for (int u = 0; u < 8; ++u) av[u] = as[k0 + u];
#pragma unroll
        for (int u = 0; u < 8; ++u) { o[u] = P; P = __expf(av[u]) * P + s[u]; }
#pragma unroll
        for (int u = 0; u < 8; ++u) pb[(size_t)(k0 + u) * (PP * NN)] = o[u];
    }
}

// ---------------------------------------------------------------------------
// K3: per segment, walk 4 chunks with register P, double-buffered pipeline:
// issue loads(cc+1) -> compute(cc) -> convert+write(cc+1) -> barrier.
// ---------------------------------------------------------------------------
__global__ __launch_bounds__(256) void k3_y(
    const float* __restrict__ X, const float* __restrict__ A,
    const float* __restrict__ Bm, const float* __restrict__ Cm,
    const float* __restrict__ pin, float* __restrict__ Y)
{
    int seg = blockIdx.x;
    int chain = seg >> 5;
    int kseg = seg & (NSEG - 1);
    int h = chain & (HH - 1);
    int b = chain >> 5;
    int tid = threadIdx.x;
    int w = tid >> 6, l = tid & 63, g = l >> 4, lr = l & 15;

    __shared__ short XTF[2][8 * 64 * 8];   // X^T B-frags, dbuf (16 KB)
    __shared__ short ScF[8 * 64 * 8];      // score A-frags, wave-private (8 KB)
    __shared__ float Bs[2][LL][17];        // plain B, dbuf (8.7 KB)
    __shared__ short PT16[2][NN * 68];     // P^T bf16, dbuf (4.4 KB)
    __shared__ float csL[2][LL];
    __shared__ float wls[2][LL];

    // zero ScF once (upper-triangular tiles never written stay zero)
    ((bf16x8*)ScF)[tid] = (bf16x8)0;
    ((bf16x8*)ScF)[tid + 256] = (bf16x8)0;

    float4 pv = *(const float4*)(pin + (size_t)seg * (PP * NN) + (16 * w + lr) * NN + 4 * g);
    float P[4] = {pv.x, pv.y, pv.z, pv.w};

    float xr[16]; float4 br, cr0, cr1; float ar = 0.f;
    bf16x8 caw;

    int c0 = kseg * SEG;

    auto LOADS = [&](int c) {
        size_t row0 = (size_t)b * SS + (size_t)c * LL;
        const float* Xp = X + (row0 * HH + h) * PP;
        const float* Bp = Bm + (row0 * HH + h) * NN;
        const float* Cp = Cm + (row0 * HH + h) * NN;
        const float* Ap = A + row0 * HH + h;
#pragma unroll
        for (int si = 0; si < 2; ++si) {
            int s = tid + si * 256;
            int sl = s & 63, pt = (s >> 6) & 3, kt = s >> 8;
            int pp2 = pt * 16 + (sl & 15);
            int k0 = kt * 32 + (sl >> 4) * 8;
#pragma unroll
            for (int e = 0; e < 8; ++e)
                xr[si * 8 + e] = Xp[(size_t)(k0 + e) * (HH * PP) + pp2];
        }
        br = *(const float4*)(Bp + (size_t)(tid >> 2) * (HH * NN) + (tid & 3) * 4);
        if (g < 2) {
            const float* crp = Cp + (size_t)(16 * w + lr) * (HH * NN) + g * 8;
            cr0 = *(const float4*)crp;
            cr1 = *(const float4*)(crp + 4);
        }
        if (tid < 64) ar = Ap[(size_t)tid * HH];
    };

    auto WRITE = [&](int q1) {
        if (tid < 64) {
            float x = ar;
#pragma unroll
            for (int d = 1; d < 64; d <<= 1) {
                float t = __shfl_up(x, d, 64);
                if (tid >= d) x += t;
            }
            csL[q1][tid] = x;
            float al2 = __shfl(x, 63, 64);
            wls[q1][tid] = __expf(al2 - x);
        }
        {
            int r = tid >> 2, qq = tid & 3;
            Bs[q1][r][qq * 4 + 0] = br.x;
            Bs[q1][r][qq * 4 + 1] = br.y;
            Bs[q1][r][qq * 4 + 2] = br.z;
            Bs[q1][r][qq * 4 + 3] = br.w;
        }
#pragma unroll
        for (int si = 0; si < 2; ++si) {
            int s = tid + si * 256;
            bf16x8 xb;
#pragma unroll
            for (int e = 0; e < 8; ++e) xb[e] = f2bf(xr[si * 8 + e]);
            ((bf16x8*)(XTF[q1]))[s] = xb;
        }
#pragma unroll
        for (int r = 0; r < 4; ++r)
            PT16[q1][(4 * g + r) * 68 + 16 * w + lr] = f2bf(P[r]);
        bf16x8 t = (bf16x8)0;
        if (g < 2) {
            t[0] = f2bf(cr0.x); t[1] = f2bf(cr0.y); t[2] = f2bf(cr0.z); t[3] = f2bf(cr0.w);
            t[4] = f2bf(cr1.x); t[5] = f2bf(cr1.y); t[6] = f2bf(cr1.z); t[7] = f2bf(cr1.w);
        }
        caw = t;
    };

    LOADS(c0);
    WRITE(0);
    __syncthreads();

    for (int cc = 0; cc < SEG; ++cc) {
        int q = cc & 1;
        if (cc + 1 < SEG) LOADS(c0 + cc + 1);   // prefetch next chunk -> regs

        // ---- compute chunk cc from buffers [q] ----
        float alast = csL[q][LL - 1];
        float cs_i[4], ei[4];
        int ib = 16 * w + 4 * g;
#pragma unroll
        for (int r = 0; r < 4; ++r) { cs_i[r] = csL[q][ib + r]; ei[r] = __expf(cs_i[r]); }

        bf16x8 pf[4];
#pragma unroll
        for (int pt = 0; pt < 4; ++pt) {
            bf16x8 t = (bf16x8)0;
            if (g < 2) {
#pragma unroll
                for (int e = 0; e < 8; ++e)
                    t[e] = PT16[q][(g * 8 + e) * 68 + pt * 16 + lr];
            }
            pf[pt] = t;
        }
        bf16x8 bt[2];
#pragma unroll
        for (int kt = 0; kt < 2; ++kt) {
            bf16x8 t;
#pragma unroll
            for (int e = 0; e < 8; ++e) {
                int ll2 = kt * 32 + g * 8 + e;
                t[e] = f2bf(Bs[q][ll2][lr] * wls[q][ll2]);
            }
            bt[kt] = t;
        }

        // scores: Sc[i][j] = (C[i]·B[j]) * exp(cs_i - cs_j), j<=i
        for (int jt = 0; jt <= w; ++jt) {
            bf16x8 bw = (bf16x8)0;
            if (g < 2) {
#pragma unroll
                for (int e = 0; e < 8; ++e)
                    bw[e] = f2bf(Bs[q][jt * 16 + lr][g * 8 + e]);
            }
            f32x4 sr = __builtin_amdgcn_mfma_f32_16x16x32_bf16(caw, bw, (f32x4)0.f, 0, 0, 0);
            int j = jt * 16 + lr;
            float csj = csL[q][j];
            int kt2 = j >> 5;
            int flb = 16 * ((j >> 3) & 3);
#pragma unroll
            for (int r = 0; r < 4; ++r) {
                int i15 = g * 4 + r;
                int i = 16 * w + i15;
                float v = (j <= i) ? sr[r] * __expf(cs_i[r] - csj) : 0.f;
                ScF[((w * 2 + kt2) * 64 + i15 + flb) * 8 + (j & 7)] = f2bf(v);
            }
        }

        // Yoff: acc = C·P^T, scaled by exp(cs_i)
        f32x4 acc[4];
#pragma unroll
        for (int pt = 0; pt < 4; ++pt)
            acc[pt] = __builtin_amdgcn_mfma_f32_16x16x32_bf16(caw, pf[pt], (f32x4)0.f, 0, 0, 0);
#pragma unroll
        for (int pt = 0; pt < 4; ++pt)
#pragma unroll
            for (int r = 0; r < 4; ++r) acc[pt][r] *= ei[r];

        // Ydiag: acc += Sc·X
        int kts = (w >= 2) ? 2 : 1;
        for (int kt = 0; kt < kts; ++kt) {
            bf16x8 af = ((bf16x8*)ScF)[(w * 2 + kt) * 64 + l];
#pragma unroll
            for (int pt = 0; pt < 4; ++pt) {
                bf16x8 xf = ((bf16x8*)(XTF[q]))[(kt * 4 + pt) * 64 + l];
                acc[pt] = __builtin_amdgcn_mfma_f32_16x16x32_bf16(af, xf, acc[pt], 0, 0, 0);
            }
        }

        // S^T update of P
        f32x4 st = (f32x4)0.f;
#pragma unroll
        for (int kt = 0; kt < 2; ++kt) {
            bf16x8 xf = ((bf16x8*)(XTF[q]))[(kt * 4 + w) * 64 + l];
            st = __builtin_amdgcn_mfma_f32_16x16x32_bf16(bt[kt], xf, st, 0, 0, 0);
        }
        float ea = __expf(alast);
#pragma unroll
        for (int r = 0; r < 4; ++r) P[r] = ea * P[r] + st[r];

        // store Y
        {
            size_t row0 = (size_t)b * SS + (size_t)(c0 + cc) * LL;
            float* Yp = Y + (row0 * HH + h) * PP;
#pragma unroll
            for (int pt = 0; pt < 4; ++pt)
#pragma unroll
                for (int r = 0; r < 4; ++r)
                    Yp[(size_t)(16 * w + 4 * g + r) * (HH * PP) + pt * 16 + lr] = acc[pt][r];
        }

        if (cc + 1 < SEG) WRITE(q ^ 1);   // convert prefetched regs -> buffers [q^1]
        __syncthreads();
    }
}

// ---------------------------------------------------------------------------
extern "C" void kernel_launch(void* const* d_in, const int* in_sizes, int n_in,
                              void* d_out, int out_size, void* d_ws, size_t ws_size,
                              hipStream_t stream)
{
    const float* X = (const float*)d_in[0];
    const float* A = (const float*)d_in[1];
    const float* B = (const float*)d_in[2];
    const float* C = (const float*)d_in[3];
    float* Y = (float*)d_out;

    float* carry = (float*)d_ws;                              // 16 MiB
    float* pin   = carry + (size_t)NSEGT * (PP * NN);         // 16 MiB
    float* segd  = pin   + (size_t)NSEGT * (PP * NN);         // 16 KiB

    dim3 blk(256);
    k1_carries<<<dim3(NSEGT), blk, 0, stream>>>(X, A, B, carry, segd);
    k2_scan<<<dim3(NCHAIN * 4), blk, 0, stream>>>(carry, segd, pin);
    k3_y<<<dim3(NSEGT), blk, 0, stream>>>(X, A, B, C, pin, Y);
}

// Round 5
// 275.912 us; speedup vs baseline: 1.2397x; 1.0381x over previous
//
#include <hip/hip_runtime.h>

// Mamba-2 SSD chunked scan. b=4, s=8192, h=32, p=64, n=16, l=64, c=128.
// k1: segment walk -> per-chunk prefix states Plocal/dsum + segment carries.
// k2: scan segment carries -> pin.
// k3: fully independent per-chunk blocks (16384), MFMA, one barrier.
#define BB 4
#define SS 8192
#define HH 32
#define PP 64
#define NN 16
#define LL 64
#define CC 128
#define SEG 4
#define NSEG (CC / SEG)          // 32 segments per chain
#define NCHAIN (BB * HH)         // 128 chains
#define NSEGT (NCHAIN * NSEG)    // 4096 segments
#define NCHT (NCHAIN * CC)       // 16384 chunks

typedef __attribute__((ext_vector_type(8))) short bf16x8;
typedef __attribute__((ext_vector_type(4))) short bf16x4;
typedef __attribute__((ext_vector_type(4))) float f32x4;

__device__ inline short f2bf(float f) {
    unsigned u = __builtin_bit_cast(unsigned, f);
    u = (u + 0x7FFFu + ((u >> 16) & 1u)) >> 16;
    return (short)u;
}

// ---------------------------------------------------------------------------
// K1: per segment, pipelined chunk walk. Emits Plocal/dsum per chunk (cc>0),
// final carry + asum per segment.
// ---------------------------------------------------------------------------
__global__ __launch_bounds__(256) void k1_carries(
    const float* __restrict__ X, const float* __restrict__ A,
    const float* __restrict__ B, float* __restrict__ carry,
    float* __restrict__ segd, float* __restrict__ ploc,
    float* __restrict__ dsum)
{
    int seg = blockIdx.x;
    int chain = seg >> 5;            // / NSEG
    int kseg = seg & (NSEG - 1);
    int h = chain & (HH - 1);
    int b = chain >> 5;
    int tid = threadIdx.x;
    int w = tid >> 6, l = tid & 63, g = l >> 4, lr = l & 15;

    __shared__ float Bs[2][LL][17];
    __shared__ float csL[2][LL];
    __shared__ float wls[2][LL];

    float P[4] = {0.f, 0.f, 0.f, 0.f};
    float asum = 0.f;
    float xr[16]; float4 br; float ar = 0.f;

    int c0 = kseg * SEG;
    int pnoff = (16 * w + lr) * NN + 4 * g;

    auto LOADS = [&](int c) {
        size_t row0 = (size_t)b * SS + (size_t)c * LL;
        const float* Xp = X + (row0 * HH + h) * PP;
        const float* Bp = B + (row0 * HH + h) * NN;
        const float* Ap = A + row0 * HH + h;
#pragma unroll
        for (int kt = 0; kt < 2; ++kt)
#pragma unroll
            for (int e = 0; e < 8; ++e)
                xr[kt * 8 + e] = Xp[(size_t)(kt * 32 + g * 8 + e) * (HH * PP) + 16 * w + lr];
        br = *(const float4*)(Bp + (size_t)(tid >> 2) * (HH * NN) + (tid & 3) * 4);
        if (tid < 64) ar = Ap[(size_t)tid * HH];
    };

    auto WRITE = [&](int q1) {
        if (tid < 64) {
            float x = ar;
#pragma unroll
            for (int d = 1; d < 64; d <<= 1) {
                float t = __shfl_up(x, d, 64);
                if (tid >= d) x += t;
            }
            csL[q1][tid] = x;
            float al2 = __shfl(x, 63, 64);
            wls[q1][tid] = __expf(al2 - x);
        }
        int r = tid >> 2, qq = tid & 3;
        Bs[q1][r][qq * 4 + 0] = br.x;
        Bs[q1][r][qq * 4 + 1] = br.y;
        Bs[q1][r][qq * 4 + 2] = br.z;
        Bs[q1][r][qq * 4 + 3] = br.w;
    };

    LOADS(c0);
    WRITE(0);
    __syncthreads();

    for (int cc = 0; cc < SEG; ++cc) {
        int q = cc & 1;
        // publish prefix state for chunk c0+cc (cc==0 prefix is pin alone)
        if (cc > 0) {
            float4 pv = {P[0], P[1], P[2], P[3]};
            *(float4*)(ploc + (size_t)(chain * CC + c0 + cc) * (PP * NN) + pnoff) = pv;
            if (tid == 0) dsum[chain * CC + c0 + cc] = asum;
        }
        // convert own X strip first (frees xr for the next prefetch)
        bf16x8 xf0, xf1;
#pragma unroll
        for (int e = 0; e < 8; ++e) { xf0[e] = f2bf(xr[e]); xf1[e] = f2bf(xr[8 + e]); }
        if (cc + 1 < SEG) LOADS(c0 + cc + 1);

        bf16x8 bt[2];
#pragma unroll
        for (int kt = 0; kt < 2; ++kt) {
            bf16x8 t;
#pragma unroll
            for (int e = 0; e < 8; ++e) {
                int ll2 = kt * 32 + g * 8 + e;
                t[e] = f2bf(Bs[q][ll2][lr] * wls[q][ll2]);
            }
            bt[kt] = t;
        }
        f32x4 st = __builtin_amdgcn_mfma_f32_16x16x32_bf16(bt[0], xf0, (f32x4)0.f, 0, 0, 0);
        st = __builtin_amdgcn_mfma_f32_16x16x32_bf16(bt[1], xf1, st, 0, 0, 0);

        float alast = csL[q][LL - 1];
        float ea = __expf(alast);
#pragma unroll
        for (int r = 0; r < 4; ++r) P[r] = ea * P[r] + st[r];
        asum += alast;

        if (cc + 1 < SEG) WRITE(q ^ 1);
        __syncthreads();
    }

    float4 pv = {P[0], P[1], P[2], P[3]};
    *(float4*)(carry + (size_t)seg * (PP * NN) + pnoff) = pv;
    if (tid == 0) segd[seg] = asum;
}

// ---------------------------------------------------------------------------
// K2: per chain, scan NSEG=32 segment carries -> incoming prefix per segment.
// ---------------------------------------------------------------------------
__global__ __launch_bounds__(256) void k2_scan(
    const float* __restrict__ carry, const float* __restrict__ segd,
    float* __restrict__ pin)
{
    int chain = blockIdx.x >> 2;
    int t = ((blockIdx.x & 3) << 8) + threadIdx.x;    // 0..1023
    const float* cb = carry + (size_t)chain * NSEG * (PP * NN) + t;
    float* pb = pin + (size_t)chain * NSEG * (PP * NN) + t;
    const float* as = segd + chain * NSEG;
    float P = 0.f;
    for (int k0 = 0; k0 < NSEG; k0 += 8) {
        float s[8], av[8], o[8];
#pragma unroll
        for (int u = 0; u < 8; ++u) s[u] = cb[(size_t)(k0 + u) * (PP * NN)];
#pragma unroll
        for (int u = 0; u < 8; ++u) av[u] = as[k0 + u];
#pragma unroll
        for (int u = 0; u < 8; ++u) { o[u] = P; P = __expf(av[u]) * P + s[u]; }
#pragma unroll
        for (int u = 0; u < 8; ++u) pb[(size_t)(k0 + u) * (PP * NN)] = o[u];
    }
}

// ---------------------------------------------------------------------------
// K3: one block per chunk (16384 blocks). Stage -> 1 barrier -> compute.
// P_c = exp(dsum_c)*pin[seg] + Plocal_c. All MFMA operands fragment-staged.
// ---------------------------------------------------------------------------
__global__ __launch_bounds__(256) void k3_y(
    const float* __restrict__ X, const float* __restrict__ A,
    const float* __restrict__ Bm, const float* __restrict__ Cm,
    const float* __restrict__ pin, const float* __restrict__ ploc,
    const float* __restrict__ dsum, float* __restrict__ Y)
{
    int blk = blockIdx.x;
    int h = blk & (HH - 1);
    int c = (blk >> 5) & (CC - 1);
    int b = blk >> 12;
    int tid = threadIdx.x;
    int w = tid >> 6, l = tid & 63, g = l >> 4, lr = l & 15;
    int chain = b * HH + h;
    int seg = chain * NSEG + (c >> 2);

    __shared__ short XTF[8 * 64 * 8];   // X^T B-frags (8 KB)
    __shared__ short ScF[8 * 64 * 8];   // score A-frags, wave-private (8 KB)
    __shared__ short BsF[4 * 64 * 8];   // B B-frags (4 KB)
    __shared__ short PF[4 * 64 * 8];    // P B-frags (4 KB)
    __shared__ float csL[LL];

    size_t row0 = (size_t)b * SS + (size_t)c * LL;
    const float* Xp = X + (row0 * HH + h) * PP;
    const float* Bp = Bm + (row0 * HH + h) * NN;
    const float* Cp = Cm + (row0 * HH + h) * NN;
    const float* Ap = A + row0 * HH + h;
    float* Yp = Y + (row0 * HH + h) * PP;

    // ---- issue global loads ----
    float xr[16];
#pragma unroll
    for (int si = 0; si < 2; ++si) {
        int k0 = si * 32 + g * 8;
#pragma unroll
        for (int e = 0; e < 8; ++e)
            xr[si * 8 + e] = Xp[(size_t)(k0 + e) * (HH * PP) + 16 * w + lr];
    }
    int r = tid >> 2, q = tid & 3;
    float4 br = *(const float4*)(Bp + (size_t)r * (HH * NN) + q * 4);
    float4 cr0 = {0,0,0,0}, cr1 = {0,0,0,0};
    if (g < 2) {
        const float* crp = Cp + (size_t)(16 * w + lr) * (HH * NN) + g * 8;
        cr0 = *(const float4*)crp;
        cr1 = *(const float4*)(crp + 4);
    }
    float ar = 0.f;
    if (tid < 64) ar = Ap[(size_t)tid * HH];
    int pnoff = (16 * w + lr) * NN + 4 * g;
    float4 pinv = *(const float4*)(pin + (size_t)seg * (PP * NN) + pnoff);
    float P4[4];
    if ((c & (SEG - 1)) == 0) {
        P4[0] = pinv.x; P4[1] = pinv.y; P4[2] = pinv.z; P4[3] = pinv.w;
    } else {
        float4 plv = *(const float4*)(ploc + (size_t)(chain * CC + c) * (PP * NN) + pnoff);
        float ed = __expf(dsum[chain * CC + c]);
        P4[0] = ed * pinv.x + plv.x;
        P4[1] = ed * pinv.y + plv.y;
        P4[2] = ed * pinv.z + plv.z;
        P4[3] = ed * pinv.w + plv.w;
    }

    // ---- LDS staging ----
    ((bf16x8*)ScF)[tid] = (bf16x8)0;           // zero (upper-tri tiles)
    ((bf16x8*)ScF)[tid + 256] = (bf16x8)0;
    if (tid < 128)                              // zero PF k>=16 half
        ((bf16x8*)PF)[(tid >> 5) * 64 + 32 + (tid & 31)] = (bf16x8)0;

#pragma unroll
    for (int si = 0; si < 2; ++si) {
        bf16x8 xb;
#pragma unroll
        for (int e = 0; e < 8; ++e) xb[e] = f2bf(xr[si * 8 + e]);
        ((bf16x8*)XTF)[tid + si * 256] = xb;    // slot (si*4+w)*64+l == tid+si*256
    }
    {
        int fl = (r & 15) + 16 * (q >> 1);
        int jt = r >> 4;
        bf16x4 bb = { f2bf(br.x), f2bf(br.y), f2bf(br.z), f2bf(br.w) };
        ((bf16x4*)BsF)[(jt * 64 + fl) * 2 + (q & 1)] = bb;
        int zt = tid >> 6, zu = (tid >> 1) & 31, zv = tid & 1;
        ((bf16x4*)BsF)[(zt * 64 + 32 + zu) * 2 + zv] = (bf16x4)0;
    }
#pragma unroll
    for (int rr = 0; rr < 4; ++rr) {
        int n = 4 * g + rr;
        PF[(w * 64 + (n >> 3) * 16 + lr) * 8 + (n & 7)] = f2bf(P4[rr]);
    }
    bf16x8 caw = (bf16x8)0;
    if (g < 2) {
        caw[0] = f2bf(cr0.x); caw[1] = f2bf(cr0.y);
        caw[2] = f2bf(cr0.z); caw[3] = f2bf(cr0.w);
        caw[4] = f2bf(cr1.x); caw[5] = f2bf(cr1.y);
        caw[6] = f2bf(cr1.z); caw[7] = f2bf(cr1.w);
    }
    if (tid < 64) {
        float x = ar;
#pragma unroll
        for (int d = 1; d < 64; d <<= 1) {
            float t = __shfl_up(x, d, 64);
            if (tid >= d) x += t;
        }
        csL[tid] = x;
    }
    __syncthreads();

    // ---- compute ----
    float cs_i[4], ei[4];
    int ib = 16 * w + 4 * g;
#pragma unroll
    for (int rr = 0; rr < 4; ++rr) { cs_i[rr] = csL[ib + rr]; ei[rr] = __expf(cs_i[rr]); }

    // scores: Sc[i][j] = (C[i]·B[j]) * exp(cs_i - cs_j), j<=i
    for (int jt = 0; jt <= w; ++jt) {
        bf16x8 bw = ((bf16x8*)BsF)[jt * 64 + l];
        f32x4 sr = __builtin_amdgcn_mfma_f32_16x16x32_bf16(caw, bw, (f32x4)0.f, 0, 0, 0);
        int j = jt * 16 + lr;
        float csj = csL[j];
        int kt2 = j >> 5;
        int flb = 16 * ((j >> 3) & 3);
#pragma unroll
        for (int rr = 0; rr < 4; ++rr) {
            int i15 = g * 4 + rr;
            int i = 16 * w + i15;
            float v = (j <= i) ? sr[rr] * __expf(cs_i[rr] - csj) : 0.f;
            ScF[((w * 2 + kt2) * 64 + i15 + flb) * 8 + (j & 7)] = f2bf(v);
        }
    }

    // Yoff: acc = C·P^T scaled by exp(cs_i)
    f32x4 acc[4];
#pragma unroll
    for (int pt = 0; pt < 4; ++pt) {
        bf16x8 pfv = ((bf16x8*)PF)[pt * 64 + l];
        acc[pt] = __builtin_amdgcn_mfma_f32_16x16x32_bf16(caw, pfv, (f32x4)0.f, 0, 0, 0);
    }
#pragma unroll
    for (int pt = 0; pt < 4; ++pt)
#pragma unroll
        for (int rr = 0; rr < 4; ++rr) acc[pt][rr] *= ei[rr];

    // Ydiag: acc += Sc·X
    int kts = (w >= 2) ? 2 : 1;
    for (int kt = 0; kt < kts; ++kt) {
        bf16x8 af = ((bf16x8*)ScF)[(w * 2 + kt) * 64 + l];
#pragma unroll
        for (int pt = 0; pt < 4; ++pt) {
            bf16x8 xf = ((bf16x8*)XTF)[(kt * 4 + pt) * 64 + l];
            acc[pt] = __builtin_amdgcn_mfma_f32_16x16x32_bf16(af, xf, acc[pt], 0, 0, 0);
        }
    }

    // store Y: i = 16w + 4g + rr, p = 16pt + lr
#pragma unroll
    for (int pt = 0; pt < 4; ++pt)
#pragma unroll
        for (int rr = 0; rr < 4; ++rr)
            Yp[(size_t)(16 * w + 4 * g + rr) * (HH * PP) + pt * 16 + lr] = acc[pt][rr];
}

// ---------------------------------------------------------------------------
extern "C" void kernel_launch(void* const* d_in, const int* in_sizes, int n_in,
                              void* d_out, int out_size, void* d_ws, size_t ws_size,
                              hipStream_t stream)
{
    const float* X = (const float*)d_in[0];
    const float* A = (const float*)d_in[1];
    const float* B = (const float*)d_in[2];
    const float* C = (const float*)d_in[3];
    float* Y = (float*)d_out;

    float* carry = (float*)d_ws;                               // 16 MiB
    float* pin   = carry + (size_t)NSEGT * (PP * NN);          // 16 MiB
    float* ploc  = pin   + (size_t)NSEGT * (PP * NN);          // 64 MiB
    float* segd  = ploc  + (size_t)NCHT * (PP * NN);           // 16 KiB
    float* dsum  = segd  + NSEGT;                              // 64 KiB

    dim3 blk(256);
    k1_carries<<<dim3(NSEGT), blk, 0, stream>>>(X, A, B, carry, segd, ploc, dsum);
    k2_scan<<<dim3(NCHAIN * 4), blk, 0, stream>>>(carry, segd, pin);
    k3_y<<<dim3(NCHT), blk, 0, stream>>>(X, A, B, C, pin, ploc, dsum, Y);
}